// Round 9
// baseline (115.177 us; speedup 1.0000x reference)
//
#include <hip/hip_runtime.h>
#include <hip/hip_bf16.h>

#define M_ROWS 8192
#define K_DIM 128
#define NCLS 60
#define NSLOT 64           // 64 column slots of 128 cols each
#define NSLAB 128          // kclass partial tables

// x = q_i . q_j where q = bf16(fhat * SCL), SCL^2 = 5*log2(e)  ->  sim = x*ln2, exp(sim) = 2^x
constexpr float SCL = 2.68579007f;     // sqrt(5 * 1.4426950408889634)
constexpr float LN2 = 0.69314718056f;

using f32x4 = __attribute__((ext_vector_type(4))) float;
using s16x8 = __attribute__((ext_vector_type(8))) short;

__device__ inline float bf2f(ushort u) {
    union { unsigned int i; float f; } v; v.i = ((unsigned int)u) << 16; return v.f;
}
__device__ inline float fexp2(float x) {
#if __has_builtin(__builtin_amdgcn_exp2f)
    return __builtin_amdgcn_exp2f(x);
#else
    return exp2f(x);
#endif
}

// ---------------- row L2-normalize, scale, f32 -> bf16 (16 rows/block) ----------------
__global__ __launch_bounds__(256) void knorm(const float* __restrict__ feat, ushort* __restrict__ fn) {
    const int wv = threadIdx.x >> 6, lane = threadIdx.x & 63;
    int row = blockIdx.x * 16 + wv * 4;
#pragma unroll
    for (int it = 0; it < 4; ++it, ++row) {
        const float2 v = *(const float2*)&feat[(size_t)row * K_DIM + lane * 2];
        float ss = v.x * v.x + v.y * v.y;
#pragma unroll
        for (int m = 1; m < 64; m <<= 1) ss += __shfl_xor(ss, m, 64);
        const float rs = rsqrtf(ss) * SCL;
        __hip_bfloat16 ha = __float2bfloat16(v.x * rs);
        __hip_bfloat16 hb = __float2bfloat16(v.y * rs);
        ushort2 o;
        o.x = *reinterpret_cast<const ushort*>(&ha);
        o.y = *reinterpret_cast<const ushort*>(&hb);
        *(ushort2*)&fn[(size_t)row * K_DIM + lane * 2] = o;
    }
}

// ---------------- class partials: 128 blocks x 64 rows, LDS table -> slab ----------------
__global__ __launch_bounds__(256) void kclassp(const ushort* __restrict__ fn,
                                               const int* __restrict__ labels,
                                               float* __restrict__ slabS,
                                               float* __restrict__ slabC) {
    __shared__ float Sl[NCLS * K_DIM];   // 30 KB
    __shared__ float Cl[NCLS];
    __shared__ int lab[64];
    const int tid = threadIdx.x;
    const int rbase = blockIdx.x * 64;
    for (int i = tid; i < NCLS * K_DIM; i += 256) Sl[i] = 0.f;
    if (tid < NCLS) Cl[tid] = 0.f;
    if (tid < 64) lab[tid] = labels[rbase + tid];
    __syncthreads();

    const int rsub = tid >> 4;           // 16 rows concurrent
    const int kc = tid & 15;             // 16 lanes x 8 bf16 = 128 k
#pragma unroll
    for (int it = 0; it < 4; ++it) {
        const int r = it * 16 + rsub;
        const int lb = lab[r];
        if (kc == 0) atomicAdd(&Cl[lb], 1.f);
        const s16x8 q = *(const s16x8*)&fn[(size_t)(rbase + r) * K_DIM + kc * 8];
        float* dst = &Sl[lb * K_DIM + kc * 8];
#pragma unroll
        for (int j = 0; j < 8; ++j) atomicAdd(&dst[j], bf2f((ushort)q[j]));
    }
    __syncthreads();
    float* oS = slabS + (size_t)blockIdx.x * (NCLS * K_DIM);
    for (int i = tid; i < NCLS * K_DIM; i += 256) oS[i] = Sl[i];
    if (tid < NCLS) slabC[blockIdx.x * 64 + tid] = Cl[tid];
}

// ---------------- reduce slabs -> S, cntC; also zeroes out ----------------
__global__ __launch_bounds__(256) void kreduce(const float* __restrict__ slabS,
                                               const float* __restrict__ slabC,
                                               float* __restrict__ S,
                                               float* __restrict__ cntC,
                                               float* __restrict__ out) {
    const int i = blockIdx.x * 256 + threadIdx.x;
    if (i == 0) out[0] = 0.f;
    if (i < NCLS * K_DIM) {
        float s = 0.f;
#pragma unroll 8
        for (int b = 0; b < NSLAB; ++b) s += slabS[(size_t)b * (NCLS * K_DIM) + i];
        S[i] = s;
    } else if (i < NCLS * K_DIM + NCLS) {
        const int c = i - NCLS * K_DIM;
        float s = 0.f;
#pragma unroll 8
        for (int b = 0; b < NSLAB; ++b) s += slabC[b * 64 + c];
        cntC[c] = s;
    }
}

// ---------------- main: denomP[slot][i] = sum_{j in slot} 2^(q_i.q_j) ----------------
// No LDS, no barriers, no atomics. Sized for 4 waves/SIMD (~100 unified regs):
// wave tile = 32 rows x 64 cols, block = 2x2 wave quadrants (64 rows x 2 slots).
// Grid: (128 row-groups, 32 strip-pairs) = 4096 blocks -> 16 blocks/CU queued.
__global__ __launch_bounds__(256, 4) void kmain(const ushort* __restrict__ fn,
                                                float* __restrict__ denomP) {
    const int tid = threadIdx.x;
    const int lane = tid & 63;
    const int lrow = lane & 15;
    const int g = lane >> 4;
    const int wv = tid >> 6;
    const int rbase = blockIdx.x * 64 + (wv >> 1) * 32;  // this wave's first row
    const int slot = blockIdx.y * 2 + (wv & 1);          // this wave's 128-col slot
    const int c0 = slot * 128;

    // persistent A fragments: rows rbase..+31, K=128  (2 m-frags x 4 kk = 32 VGPR)
    s16x8 af[2][4];
#pragma unroll
    for (int m = 0; m < 2; ++m)
#pragma unroll
        for (int kk = 0; kk < 4; ++kk)
            af[m][kk] = *(const s16x8*)&fn[(size_t)(rbase + m * 16 + lrow) * K_DIM + kk * 32 + g * 8];

    float pd[2][4] = {};  // per-thread row partials over the slot

#pragma unroll
    for (int t = 0; t < 2; ++t) {   // 2 tiles of 64 cols
        const int ct = c0 + t * 64;
        f32x4 acc[2][4] = {};
#pragma unroll
        for (int kk = 0; kk < 4; ++kk) {
            s16x8 bfr[4];
#pragma unroll
            for (int n = 0; n < 4; ++n)
                bfr[n] = *(const s16x8*)&fn[(size_t)(ct + n * 16 + lrow) * K_DIM + kk * 32 + g * 8];
#pragma unroll
            for (int m = 0; m < 2; ++m)
#pragma unroll
                for (int n = 0; n < 4; ++n)
                    acc[m][n] = __builtin_amdgcn_mfma_f32_16x16x32_bf16(af[m][kk], bfr[n], acc[m][n], 0, 0, 0);
        }
#pragma unroll
        for (int m = 0; m < 2; ++m)
#pragma unroll
            for (int n = 0; n < 4; ++n)
#pragma unroll
                for (int r = 0; r < 4; ++r)
                    pd[m][r] += fexp2(acc[m][n][r]);
    }

    // reduce across the 16 column-lanes; plain store (wave owns row x slot)
#pragma unroll
    for (int m = 0; m < 2; ++m)
#pragma unroll
        for (int r = 0; r < 4; ++r) {
            float v = pd[m][r];
#pragma unroll
            for (int msk = 1; msk < 16; msk <<= 1) v += __shfl_xor(v, msk, 16);
            if (lrow == 0)
                denomP[(size_t)slot * M_ROWS + rbase + m * 16 + g * 4 + r] = v;
        }
}

// ---------------- finalize: per-row loss, mean ----------------
__global__ __launch_bounds__(1024) void kfin(const ushort* __restrict__ fn,
                                             const int* __restrict__ labels,
                                             const float* __restrict__ denomP,
                                             const float* __restrict__ S,
                                             const float* __restrict__ cntC,
                                             float* __restrict__ out) {
    const int tid = threadIdx.x;
    const int wv = tid >> 6, lane = tid & 63;
    const int row = blockIdx.x * 16 + wv;
    const ushort2 qv = *(const ushort2*)&fn[(size_t)row * K_DIM + lane * 2];
    const float f0 = bf2f(qv.x), f1 = bf2f(qv.y);
    const int c = labels[row];
    const float2 sv = *(const float2*)&S[c * K_DIM + lane * 2];
    float dot = f0 * sv.x + f1 * sv.y;   // q_i . S_c  (includes self)
    float sii = f0 * f0 + f1 * f1;       // q_i . q_i
#pragma unroll
    for (int msk = 1; msk < 64; msk <<= 1) {
        dot += __shfl_xor(dot, msk, 64);
        sii += __shfl_xor(sii, msk, 64);
    }
    // gather the 64 slot partials for this row (one per lane)
    float dsum = denomP[(size_t)lane * M_ROWS + row];
#pragma unroll
    for (int msk = 1; msk < 64; msk <<= 1) dsum += __shfl_xor(dsum, msk, 64);

    __shared__ float ls[16];
    if (lane == 0) {
        const float cf = cntC[c];                                   // count incl. self
        const float d = fmaxf(dsum - fexp2(sii), 1e-5f);            // exclude diagonal
        const float p = (dot - sii) * LN2;                          // matched sims, excl diag
        ls[wv] = ((cf - 1.f) * __logf(d) - p) / cf;
    }
    __syncthreads();
    if (tid == 0) {
        float s = 0.f;
#pragma unroll
        for (int i = 0; i < 16; ++i) s += ls[i];
        atomicAdd(out, s * (1.0f / M_ROWS));
    }
}

extern "C" void kernel_launch(void* const* d_in, const int* in_sizes, int n_in,
                              void* d_out, int out_size, void* d_ws, size_t ws_size,
                              hipStream_t stream) {
    (void)in_sizes; (void)n_in; (void)out_size; (void)ws_size;
    const float* feat = (const float*)d_in[0];
    const int* labels = (const int*)d_in[2];   // d_in[1] (ious) unused: coef == 1
    float* out = (float*)d_out;
    char* ws = (char*)d_ws;
    ushort* fn = (ushort*)ws;                                   // 2 MB bf16 features
    float* denomP = (float*)(ws + (size_t)M_ROWS * K_DIM * 2);  // 64 x 8192 x 4B = 2 MB
    float* S = denomP + (size_t)NSLOT * M_ROWS;                 // 30 KB
    float* cntC = S + NCLS * K_DIM;                             // 256 B
    float* slabS = cntC + 64;                                   // 128 x 30 KB
    float* slabC = slabS + (size_t)NSLAB * NCLS * K_DIM;        // 128 x 256 B

    knorm<<<M_ROWS / 16, 256, 0, stream>>>(feat, fn);
    kclassp<<<NSLAB, 256, 0, stream>>>(fn, labels, slabS, slabC);
    kreduce<<<31, 256, 0, stream>>>(slabS, slabC, S, cntC, out);
    kmain<<<dim3(M_ROWS / 64, NSLOT / 2), 256, 0, stream>>>(fn, denomP);
    kfin<<<M_ROWS / 16, 1024, 0, stream>>>(fn, labels, denomP, S, cntC, out);
}

// Round 10
// 69.625 us; speedup vs baseline: 1.6542x; 1.6542x over previous
//
#include <hip/hip_runtime.h>
#include <hip/hip_bf16.h>

#define M_ROWS 8192
#define K_DIM 128
#define NCLS 60
#define NSTRIP 16          // column strips of 512
#define STRIPW 512
#define NSLAB 128          // kclass partial tables

// x = q_i . q_j where q = bf16(fhat * SCL), SCL^2 = 5*log2(e)  ->  sim = x*ln2, exp(sim) = 2^x
constexpr float SCL = 2.68579007f;     // sqrt(5 * 1.4426950408889634)
constexpr float LN2 = 0.69314718056f;

using f32x4 = __attribute__((ext_vector_type(4))) float;
using s16x8 = __attribute__((ext_vector_type(8))) short;

__device__ inline float bf2f(ushort u) {
    union { unsigned int i; float f; } v; v.i = ((unsigned int)u) << 16; return v.f;
}
__device__ inline float fexp2(float x) {
#if __has_builtin(__builtin_amdgcn_exp2f)
    return __builtin_amdgcn_exp2f(x);
#else
    return exp2f(x);
#endif
}

// packed fragment-major layout: ushort index = c16*2048 + kk*512 + lane*8
//   (c16 = col/16, kk = k/32, lane = g*16+lrow, 8 ushorts = lane's s16x8 chunk)

// ---------------- normalize + emit row-major fnr AND packed fnp ----------------
__global__ __launch_bounds__(256) void knorm(const float* __restrict__ feat,
                                             ushort* __restrict__ fnr,
                                             ushort* __restrict__ fnp) {
    __shared__ ushort ln[16][128];
    const int wv = threadIdx.x >> 6, lane = threadIdx.x & 63;
    int row = wv * 4;   // local row within this block's 16
#pragma unroll
    for (int it = 0; it < 4; ++it, ++row) {
        const int grow = blockIdx.x * 16 + row;
        const float2 v = *(const float2*)&feat[(size_t)grow * K_DIM + lane * 2];
        float ss = v.x * v.x + v.y * v.y;
#pragma unroll
        for (int m = 1; m < 64; m <<= 1) ss += __shfl_xor(ss, m, 64);
        const float rs = rsqrtf(ss) * SCL;
        __hip_bfloat16 ha = __float2bfloat16(v.x * rs);
        __hip_bfloat16 hb = __float2bfloat16(v.y * rs);
        ushort2 o;
        o.x = *reinterpret_cast<const ushort*>(&ha);
        o.y = *reinterpret_cast<const ushort*>(&hb);
        *(ushort2*)&fnr[(size_t)grow * K_DIM + lane * 2] = o;
        *(ushort2*)&ln[row][lane * 2] = o;
    }
    __syncthreads();
    // packed write: thread tid emits chunk (c = tid>>4, lrow = tid&15), linear 16B
    const int tid = threadIdx.x;
    const s16x8 vv = *(const s16x8*)&ln[tid & 15][(tid >> 4) * 8];
    *(s16x8*)&fnp[(size_t)blockIdx.x * 2048 + tid * 8] = vv;
}

// ---------------- class partials: 128 blocks x 64 rows, LDS table -> slab ----------------
__global__ __launch_bounds__(256) void kclassp(const ushort* __restrict__ fn,
                                               const int* __restrict__ labels,
                                               float* __restrict__ slabS,
                                               float* __restrict__ slabC) {
    __shared__ float Sl[NCLS * K_DIM];   // 30 KB
    __shared__ float Cl[NCLS];
    __shared__ int lab[64];
    const int tid = threadIdx.x;
    const int rbase = blockIdx.x * 64;
    for (int i = tid; i < NCLS * K_DIM; i += 256) Sl[i] = 0.f;
    if (tid < NCLS) Cl[tid] = 0.f;
    if (tid < 64) lab[tid] = labels[rbase + tid];
    __syncthreads();

    const int rsub = tid >> 4;           // 16 rows concurrent
    const int kc = tid & 15;             // 16 lanes x 8 bf16 = 128 k
#pragma unroll
    for (int it = 0; it < 4; ++it) {
        const int r = it * 16 + rsub;
        const int lb = lab[r];
        if (kc == 0) atomicAdd(&Cl[lb], 1.f);
        const s16x8 q = *(const s16x8*)&fn[(size_t)(rbase + r) * K_DIM + kc * 8];
        float* dst = &Sl[lb * K_DIM + kc * 8];
#pragma unroll
        for (int j = 0; j < 8; ++j) atomicAdd(&dst[j], bf2f((ushort)q[j]));
    }
    __syncthreads();
    float* oS = slabS + (size_t)blockIdx.x * (NCLS * K_DIM);
    for (int i = tid; i < NCLS * K_DIM; i += 256) oS[i] = Sl[i];
    if (tid < NCLS) slabC[blockIdx.x * 64 + tid] = Cl[tid];
}

// ---------------- reduce slabs -> S, cntC; also zeroes out ----------------
__global__ __launch_bounds__(256) void kreduce(const float* __restrict__ slabS,
                                               const float* __restrict__ slabC,
                                               float* __restrict__ S,
                                               float* __restrict__ cntC,
                                               float* __restrict__ out) {
    const int i = blockIdx.x * 256 + threadIdx.x;
    if (i == 0) out[0] = 0.f;
    if (i < NCLS * K_DIM) {
        float s = 0.f;
#pragma unroll 8
        for (int b = 0; b < NSLAB; ++b) s += slabS[(size_t)b * (NCLS * K_DIM) + i];
        S[i] = s;
    } else if (i < NCLS * K_DIM + NCLS) {
        const int c = i - NCLS * K_DIM;
        float s = 0.f;
#pragma unroll 8
        for (int b = 0; b < NSLAB; ++b) s += slabC[b * 64 + c];
        cntC[c] = s;
    }
}

// ---------------- main: denomP[s][i] = sum_{j in strip s} 2^(q_i.q_j) ----------------
// R6 geometry (best measured), but A/B fragments come from the PACKED layout:
// every wave load is base + lane*16B -> perfectly coalesced 1KB, no gather.
// Block = 4 waves x 64 rows (256 rows); grid (32 row-groups, 16 strips).
__global__ __launch_bounds__(256, 2) void kmain(const ushort* __restrict__ fnp,
                                                float* __restrict__ denomP) {
    const int tid = threadIdx.x;
    const int lane = tid & 63;
    const int lrow = lane & 15;
    const int g = lane >> 4;
    const int rbase = blockIdx.x * 256 + (tid >> 6) * 64;  // this wave's first row
    const int strip = blockIdx.y;

    // persistent A fragments: rows rbase..+63, K=128 (packed reads, lane-linear)
    s16x8 af[4][4];
#pragma unroll
    for (int m = 0; m < 4; ++m)
#pragma unroll
        for (int kk = 0; kk < 4; ++kk)
            af[m][kk] = *(const s16x8*)&fnp[(size_t)((rbase >> 4) + m) * 2048 + kk * 512 + lane * 8];

    float pd[4][4] = {};  // per-thread row partials over the strip

    for (int t = 0; t < STRIPW / 64; ++t) {   // 8 tiles of 64 cols
        const int c16b = strip * (STRIPW / 16) + t * 4;   // first 16-col block of tile
        f32x4 acc[4][4] = {};
#pragma unroll
        for (int kk = 0; kk < 4; ++kk) {
            s16x8 bfr[4];
#pragma unroll
            for (int n = 0; n < 4; ++n)
                bfr[n] = *(const s16x8*)&fnp[(size_t)(c16b + n) * 2048 + kk * 512 + lane * 8];
#pragma unroll
            for (int m = 0; m < 4; ++m)
#pragma unroll
                for (int n = 0; n < 4; ++n)
                    acc[m][n] = __builtin_amdgcn_mfma_f32_16x16x32_bf16(af[m][kk], bfr[n], acc[m][n], 0, 0, 0);
        }
#pragma unroll
        for (int m = 0; m < 4; ++m)
#pragma unroll
            for (int n = 0; n < 4; ++n)
#pragma unroll
                for (int r = 0; r < 4; ++r)
                    pd[m][r] += fexp2(acc[m][n][r]);
    }

    // reduce across the 16 column-lanes; plain store (wave owns its rows)
#pragma unroll
    for (int m = 0; m < 4; ++m)
#pragma unroll
        for (int r = 0; r < 4; ++r) {
            float v = pd[m][r];
#pragma unroll
            for (int msk = 1; msk < 16; msk <<= 1) v += __shfl_xor(v, msk, 16);
            if (lrow == 0)
                denomP[(size_t)strip * M_ROWS + rbase + m * 16 + g * 4 + r] = v;
        }
}

// ---------------- finalize: per-row loss, mean ----------------
__global__ __launch_bounds__(1024) void kfin(const ushort* __restrict__ fn,
                                             const int* __restrict__ labels,
                                             const float* __restrict__ denomP,
                                             const float* __restrict__ S,
                                             const float* __restrict__ cntC,
                                             float* __restrict__ out) {
    const int tid = threadIdx.x;
    const int wv = tid >> 6, lane = tid & 63;
    const int row = blockIdx.x * 16 + wv;
    const ushort2 qv = *(const ushort2*)&fn[(size_t)row * K_DIM + lane * 2];
    const float f0 = bf2f(qv.x), f1 = bf2f(qv.y);
    const int c = labels[row];
    const float2 sv = *(const float2*)&S[c * K_DIM + lane * 2];
    float dot = f0 * sv.x + f1 * sv.y;   // q_i . S_c  (includes self)
    float sii = f0 * f0 + f1 * f1;       // q_i . q_i
#pragma unroll
    for (int msk = 1; msk < 64; msk <<= 1) {
        dot += __shfl_xor(dot, msk, 64);
        sii += __shfl_xor(sii, msk, 64);
    }
    // gather the 16 strip partials for this row
    float dsum = (lane < NSTRIP) ? denomP[(size_t)lane * M_ROWS + row] : 0.f;
#pragma unroll
    for (int msk = 1; msk < 16; msk <<= 1) dsum += __shfl_xor(dsum, msk, 16);

    __shared__ float ls[16];
    if (lane == 0) {
        const float cf = cntC[c];                                   // count incl. self
        const float d = fmaxf(dsum - fexp2(sii), 1e-5f);            // exclude diagonal
        const float p = (dot - sii) * LN2;                          // matched sims, excl diag
        ls[wv] = ((cf - 1.f) * __logf(d) - p) / cf;
    }
    __syncthreads();
    if (tid == 0) {
        float s = 0.f;
#pragma unroll
        for (int i = 0; i < 16; ++i) s += ls[i];
        atomicAdd(out, s * (1.0f / M_ROWS));
    }
}

extern "C" void kernel_launch(void* const* d_in, const int* in_sizes, int n_in,
                              void* d_out, int out_size, void* d_ws, size_t ws_size,
                              hipStream_t stream) {
    (void)in_sizes; (void)n_in; (void)out_size; (void)ws_size;
    const float* feat = (const float*)d_in[0];
    const int* labels = (const int*)d_in[2];   // d_in[1] (ious) unused: coef == 1
    float* out = (float*)d_out;
    char* ws = (char*)d_ws;
    ushort* fnr = (ushort*)ws;                                  // 2 MB row-major bf16
    ushort* fnp = fnr + (size_t)M_ROWS * K_DIM;                 // 2 MB packed fragment-major
    float* denomP = (float*)(fnp + (size_t)M_ROWS * K_DIM);     // 16 x 8192 x 4B = 512 KB
    float* S = denomP + (size_t)NSTRIP * M_ROWS;                // 30 KB
    float* cntC = S + NCLS * K_DIM;                             // 256 B
    float* slabS = cntC + 64;                                   // 128 x 30 KB
    float* slabC = slabS + (size_t)NSLAB * NCLS * K_DIM;        // 128 x 256 B

    knorm<<<M_ROWS / 16, 256, 0, stream>>>(feat, fnr, fnp);
    kclassp<<<NSLAB, 256, 0, stream>>>(fnr, labels, slabS, slabC);
    kreduce<<<31, 256, 0, stream>>>(slabS, slabC, S, cntC, out);
    kmain<<<dim3(M_ROWS / 256, NSTRIP), 256, 0, stream>>>(fnp, denomP);
    kfin<<<M_ROWS / 16, 1024, 0, stream>>>(fnr, labels, denomP, S, cntC, out);
}